// Round 1
// baseline (381.856 us; speedup 1.0000x reference)
//
#include <hip/hip_runtime.h>

// SparseAutoEncoder: hypernetwork-generated per-sample MLP weights, fused.
// EN layers (rows in en_W2): (2000,200) lin @0, (200,100) tanh @400200, (100,10) lin @420300
// DE layers (rows in de_W2): (10,100) lin @0, (100,200) tanh @1100, (200,2000) lin @21300
// All hyper widths K = 64, batch B = 64. h layout: (b,k) b-major. xT layouts: (i,b) i-major.

// ---------------------------------------------------------------------------
// prep: transpose z (64x2000) -> zT (2000x64), and compute h_en, h_de (64x64)
// ---------------------------------------------------------------------------
__global__ __launch_bounds__(256) void prep_kernel(
    const float* __restrict__ z, const float* __restrict__ mu,
    const float* __restrict__ enW0, const float* __restrict__ enb0,
    const float* __restrict__ enW1, const float* __restrict__ enb1,
    const float* __restrict__ deW0, const float* __restrict__ deb0,
    const float* __restrict__ deW1, const float* __restrict__ deb1,
    float* __restrict__ zT, float* __restrict__ hen, float* __restrict__ hde)
{
    __shared__ float tile[64 * 65];
    __shared__ float h0s[4][64];
    const int bid  = blockIdx.x;
    const int lane = threadIdx.x & 63;
    const int g    = threadIdx.x >> 6;

    if (bid < 32) {
        // 64x64 tile transpose of z
        const int t0 = bid * 64;
        for (int bb = g; bb < 64; bb += 4) {
            int i = t0 + lane;
            tile[bb * 65 + lane] = (i < 2000) ? z[bb * 2000 + i] : 0.f;
        }
        __syncthreads();
        for (int ii = g; ii < 64; ii += 4) {
            int i = t0 + ii;
            if (i < 2000) zT[i * 64 + lane] = tile[lane * 65 + ii];
        }
    } else {
        // hypernetwork MLP: task = (which, b); lane = output neuron j
        const int task  = (bid - 32) * 4 + g;   // 0..127
        const int which = task >> 6;            // 0 = en, 1 = de
        const int b     = task & 63;
        const float* W0 = which ? deW0 : enW0;
        const float* b0 = which ? deb0 : enb0;
        const float* W1 = which ? deW1 : enW1;
        const float* b1 = which ? deb1 : enb1;
        float* hout     = which ? hde : hen;
        const int j = lane;
        float m0 = mu[b * 4 + 0], m1 = mu[b * 4 + 1], m2 = mu[b * 4 + 2], m3 = mu[b * 4 + 3];
        float v = tanhf(m0 * W0[j * 4 + 0] + m1 * W0[j * 4 + 1] +
                        m2 * W0[j * 4 + 2] + m3 * W0[j * 4 + 3] + b0[j]);
        h0s[g][j] = v;
        __syncthreads();
        float a = b1[j];
        const float* W1r = W1 + j * 64;
        #pragma unroll 8
        for (int k = 0; k < 64; ++k) a = fmaf(h0s[g][k], W1r[k], a);
        hout[b * 64 + j] = tanhf(a);
    }
}

// ---------------------------------------------------------------------------
// fused hyper-FC layer: yT[o,b] = act( sum_k h[b,k]*(T[b,k]+Wbias[o,k])
//                                      + sum_i x[b,i]*b2[o*NI+i] + b2[NO*NI+o] )
// T[b,k] = sum_i xT[i,b] * W2[(o*NI+i),k]
// lane = k; 64 accumulators (b) per lane; x broadcast via scalar loads.
// ---------------------------------------------------------------------------
template <int NI, int NO, int NSPLIT, bool TANH, bool ATOMIC>
__global__ __launch_bounds__(256, 2) void fc_kernel(
    const float* __restrict__ xT,   // NI x 64
    const float* __restrict__ h,    // 64 x 64 (b-major)
    const float* __restrict__ W2,   // layer base, (NO*NI+NO) x 64
    const float* __restrict__ b2,   // layer base, NO*NI+NO
    float* __restrict__ yT)         // NO x 64
{
    __shared__ float R[2][64 * 64];
    __shared__ float xbs[256];
    const int lane = threadIdx.x & 63;
    const int wave = __builtin_amdgcn_readfirstlane(threadIdx.x >> 6);
    const int o = blockIdx.x / NSPLIT;
    const int s = blockIdx.x % NSPLIT;
    constexpr int CH = NI / NSPLIT;      // NI divisible by NSPLIT
    const int i0 = s * CH;
    const int iend = i0 + CH;

    const float* __restrict__ Wbase = W2 + (size_t)o * NI * 64;
    const float* __restrict__ b2w   = b2 + (size_t)o * NI;

    float acc[64];
    #pragma unroll
    for (int b = 0; b < 64; ++b) acc[b] = 0.f;
    float xb_acc = 0.f;

    // main loop: waves interleave i by stride 4
    #pragma unroll 2
    for (int i = i0 + wave; i < iend; i += 4) {
        float w = Wbase[(size_t)i * 64 + lane];           // coalesced vector load (streamed)
        float xv_l = xT[i * 64 + lane];                   // lane=b role for bias-dot
        xb_acc = fmaf(xv_l, b2w[i], xb_acc);
        const float4* xr = (const float4*)(xT + i * 64);  // wave-uniform -> s_load
        #pragma unroll
        for (int q = 0; q < 16; ++q) {
            float4 xv = xr[q];
            acc[4 * q + 0] = fmaf(xv.x, w, acc[4 * q + 0]);
            acc[4 * q + 1] = fmaf(xv.y, w, acc[4 * q + 1]);
            acc[4 * q + 2] = fmaf(xv.z, w, acc[4 * q + 2]);
            acc[4 * q + 3] = fmaf(xv.w, w, acc[4 * q + 3]);
        }
    }

    xbs[wave * 64 + lane] = xb_acc;

    // pairwise cross-wave reduction of T using 32KB of LDS
    if (wave == 1) {
        #pragma unroll
        for (int b = 0; b < 64; ++b) R[0][b * 64 + lane] = acc[b];
    } else if (wave == 3) {
        #pragma unroll
        for (int b = 0; b < 64; ++b) R[1][b * 64 + lane] = acc[b];
    }
    __syncthreads();
    if (wave == 0) {
        #pragma unroll
        for (int b = 0; b < 64; ++b) acc[b] += R[0][b * 64 + lane];
    } else if (wave == 2) {
        #pragma unroll
        for (int b = 0; b < 64; ++b) acc[b] += R[1][b * 64 + lane];
    }
    __syncthreads();
    if (wave == 0) {
        #pragma unroll
        for (int b = 0; b < 64; ++b) R[0][b * 64 + lane] = acc[b];
    } else if (wave == 2) {
        #pragma unroll
        for (int b = 0; b < 64; ++b) R[1][b * 64 + lane] = acc[b];
    }
    __syncthreads();

    // k-contraction with h (factor in weight-bias row); butterfly over 64 lanes
    float wsel = 0.f;
    if (!ATOMIC || s == 0) wsel = W2[((size_t)NO * NI + o) * 64 + lane];
    float myv = 0.f;
    #pragma unroll
    for (int j = 0; j < 16; ++j) {
        int b = wave * 16 + j;
        float t = R[0][b * 64 + lane] + R[1][b * 64 + lane];
        float v = (t + wsel) * h[b * 64 + lane];
        #pragma unroll
        for (int m = 32; m >= 1; m >>= 1) v += __shfl_xor(v, m, 64);
        if (lane == j) myv = v;
    }
    if (lane < 16) {
        int b = wave * 16 + lane;
        float xbt = xbs[b] + xbs[64 + b] + xbs[128 + b] + xbs[192 + b];
        float out = myv + xbt;
        if (!ATOMIC || s == 0) out += b2[(size_t)NO * NI + o];
        if (TANH) out = tanhf(out);
        if (ATOMIC) atomicAdd(&yT[o * 64 + b], out);
        else        yT[o * 64 + b] = out;
    }
}

// ---------------------------------------------------------------------------
// finalize: d_out = [ z_reconst (64x2000 b-major) , x_enc (64x10 b-major) ]
// ---------------------------------------------------------------------------
__global__ __launch_bounds__(256) void final_kernel(
    const float* __restrict__ d3,   // 2000 x 64 (o-major)
    const float* __restrict__ y3,   // 10 x 64 (o-major)
    float* __restrict__ out)
{
    int t = blockIdx.x * 256 + threadIdx.x;
    if (t < 128000) {
        int b = t / 2000, oo = t - b * 2000;
        out[t] = d3[oo * 64 + b];
    } else if (t < 128640) {
        int u = t - 128000;
        int b = u / 10, oo = u - b * 10;
        out[t] = y3[oo * 64 + b];
    }
}

extern "C" void kernel_launch(void* const* d_in, const int* in_sizes, int n_in,
                              void* d_out, int out_size, void* d_ws, size_t ws_size,
                              hipStream_t stream)
{
    const float* z    = (const float*)d_in[0];
    const float* mu   = (const float*)d_in[1];
    const float* enW0 = (const float*)d_in[2];
    const float* enb0 = (const float*)d_in[3];
    const float* enW1 = (const float*)d_in[4];
    const float* enb1 = (const float*)d_in[5];
    const float* enW2 = (const float*)d_in[6];
    const float* enb2 = (const float*)d_in[7];
    const float* deW0 = (const float*)d_in[8];
    const float* deb0 = (const float*)d_in[9];
    const float* deW1 = (const float*)d_in[10];
    const float* deb1 = (const float*)d_in[11];
    const float* deW2 = (const float*)d_in[12];
    const float* deb2 = (const float*)d_in[13];

    float* ws  = (float*)d_ws;
    float* zT  = ws;                 // 2000*64
    float* hen = zT + 128000;        // 64*64
    float* hde = hen + 4096;         // 64*64
    float* y1  = hde + 4096;         // 200*64  (atomic target -> zeroed)
    float* y2  = y1 + 200 * 64;      // 100*64
    float* y3  = y2 + 100 * 64;      // 10*64   (x_enc, transposed)
    float* d1  = y3 + 10 * 64;       // 100*64
    float* d2  = d1 + 100 * 64;      // 200*64
    float* d3  = d2 + 200 * 64;      // 2000*64
    float* out = (float*)d_out;

    hipMemsetAsync(y1, 0, 200 * 64 * sizeof(float), stream);
    prep_kernel<<<64, 256, 0, stream>>>(z, mu, enW0, enb0, enW1, enb1,
                                        deW0, deb0, deW1, deb1, zT, hen, hde);
    // encoder
    fc_kernel<2000, 200, 8, false, true ><<<1600, 256, 0, stream>>>(zT, hen, enW2, enb2, y1);
    fc_kernel< 200, 100, 1, true,  false><<< 100, 256, 0, stream>>>(y1, hen, enW2 + (size_t)400200 * 64, enb2 + 400200, y2);
    fc_kernel< 100,  10, 1, false, false><<<  10, 256, 0, stream>>>(y2, hen, enW2 + (size_t)420300 * 64, enb2 + 420300, y3);
    // decoder
    fc_kernel<  10, 100, 1, false, false><<< 100, 256, 0, stream>>>(y3, hde, deW2, deb2, d1);
    fc_kernel< 100, 200, 1, true,  false><<< 200, 256, 0, stream>>>(d1, hde, deW2 + (size_t)1100 * 64, deb2 + 1100, d2);
    fc_kernel< 200, 2000, 1, false, false><<<2000, 256, 0, stream>>>(d2, hde, deW2 + (size_t)21300 * 64, deb2 + 21300, d3);

    final_kernel<<<(128640 + 255) / 256, 256, 0, stream>>>(d3, y3, out);
}